// Round 4
// baseline (1218.493 us; speedup 1.0000x reference)
//
#include <hip/hip_runtime.h>

#define N_NODES 500000
#define N_EDGES 8000000
#define N_GRAPHS 4096

// ---------------- binned-aggregation v2 (coalesced sort-scatter) ----------
#define NB 64                      // bins
#define BIN_SHIFT 13
#define BIN_NODES 8192             // nodes per bin
#define NBINS 62                   // ceil(N_NODES / BIN_NODES)
#define BIN_CAP 139264             // mean 131072, sigma ~359 -> +22 sigma
#define T_EDGES 8192               // edges per p1 block
#define P1_THREADS 512
#define EPT (T_EDGES / P1_THREADS) // 16
#define P1_GRID ((N_EDGES + T_EDGES - 1) / T_EDGES)   // 977
#define FXS 131072.0f              // 2^17 fixed point (25-bit field, m<250)
#define FXI (1.0f / 131072.0f)
#define M_MAX 250.0f
#define OVF_CAP 65536

// ---------------- ws layout (byte offsets) ----------------
#define OFF_CURS_A   0          // 64 u32
#define OFF_CURS_B   256
#define OFF_OVFC_A   512
#define OFF_OVFC_B   768
#define ZERO_SMALL   1024       // zero [0, ZERO_SMALL) per call
#define OFF_STARTS_A 4096       // 4097 u32 (padded)
#define OFF_STARTS_B 20736
#define OFF_MEAN_A   37376      // 12288 f32
#define OFF_MEAN_B   86528
#define OFF_OVF_A    135680     // OVF_CAP x float4
#define OFF_OVF_B    1184256
#define OFF_AGGF_A   2232832    // 1,000,000 f32
#define OFF_AGGF_B   6232832
#define OFF_BINS     10232832   // NBINS*BIN_CAP u64 = 69,074,944
#define WS_NEED (OFF_BINS + (size_t)NBINS * BIN_CAP * 8ull)  // 79,307,776

// ===========================================================================
// Pass 1: per-block counting sort by dst bin in LDS, then COALESCED flush of
// each bin's contiguous chunk to globally-reserved ranges. No scattered
// global writes (R3 showed 8B scatter costs ~64B RMW per payload), one
// returning global atomic per (block,bin) = 62K total.
// ===========================================================================
__global__ __launch_bounds__(512) void p1_kernel(
    const float* __restrict__ x, const int* __restrict__ ei,
    const float* __restrict__ ea,
    const float* __restrict__ Wf, const float* __restrict__ bfv,
    const float* __restrict__ Ws, const float* __restrict__ bsv,
    unsigned long long* __restrict__ bins, unsigned int* __restrict__ cursors,
    unsigned int* __restrict__ ovf_cnt, float4* __restrict__ ovf)
{
    __shared__ unsigned long long sorted[T_EDGES];   // 64 KB
    __shared__ unsigned int whist[8][NB];            // per-wave histograms
    __shared__ unsigned int base[NB];                // block-local exclusive prefix
    __shared__ unsigned int cur[NB];                 // running local cursor
    __shared__ unsigned int gbase[NB];               // reserved global start
    __shared__ unsigned int ntot_s;

    int t = threadIdx.x;
    int wave = t >> 6;
    int ebase = blockIdx.x * T_EDGES;

    for (int i = t; i < 8 * NB; i += P1_THREADS) ((unsigned int*)whist)[i] = 0;
    __syncthreads();

    // phase 1: histogram of dst bins (per-wave privatized)
#pragma unroll
    for (int i = 0; i < EPT; ++i) {
        int e = ebase + i * P1_THREADS + t;
        if (e < N_EDGES)
            atomicAdd(&whist[wave][((unsigned)ei[N_EDGES + e]) >> BIN_SHIFT], 1u);
    }
    __syncthreads();

    // phase 2: totals -> shuffle scan (wave 0, NB==64 lanes) -> reservations
    if (t < NB) {
        unsigned tot = 0;
#pragma unroll
        for (int w = 0; w < 8; ++w) tot += whist[w][t];
        unsigned v = tot;
#pragma unroll
        for (int off = 1; off < 64; off <<= 1) {
            unsigned u = __shfl_up(v, off);
            if (t >= off) v += u;
        }
        base[t] = v - tot;
        cur[t]  = v - tot;
        if (t == NB - 1) ntot_s = v;
        gbase[t] = tot ? atomicAdd(&cursors[t], tot) : 0u;
    }
    __syncthreads();

    // phase 3: compute messages, place into sorted LDS slots
    float wf[12], wsv[12];
#pragma unroll
    for (int i = 0; i < 12; ++i) { wf[i] = Wf[i]; wsv[i] = Ws[i]; }
    float bf0 = bfv[0], bf1 = bfv[1], bs0 = bsv[0], bs1 = bsv[1];

    for (int i = 0; i < EPT; ++i) {
        int e = ebase + i * P1_THREADS + t;
        if (e >= N_EDGES) continue;
        int src = ei[e];
        int dst = ei[N_EDGES + e];
        float2 xd = ((const float2*)x)[dst];
        float2 xs = ((const float2*)x)[src];
        float2 ev = ((const float2*)ea)[e];
        float z0 = xd.x, z1 = xd.y, z2 = xs.x, z3 = xs.y, z4 = ev.x, z5 = ev.y;

        float f0 = bf0 + z0*wf[0] + z1*wf[2] + z2*wf[4] + z3*wf[6] + z4*wf[8]  + z5*wf[10];
        float f1 = bf1 + z0*wf[1] + z1*wf[3] + z2*wf[5] + z3*wf[7] + z4*wf[9]  + z5*wf[11];
        float s0 = bs0 + z0*wsv[0] + z1*wsv[2] + z2*wsv[4] + z3*wsv[6] + z4*wsv[8]  + z5*wsv[10];
        float s1 = bs1 + z0*wsv[1] + z1*wsv[3] + z2*wsv[5] + z3*wsv[7] + z4*wsv[9]  + z5*wsv[11];

        float m0 = (1.f/(1.f+__expf(-f0))) * (fmaxf(s0,0.f) + __logf(1.f+__expf(-fabsf(s0))));
        float m1 = (1.f/(1.f+__expf(-f1))) * (fmaxf(s1,0.f) + __logf(1.f+__expf(-fabsf(s1))));

        int b = (int)((unsigned)dst >> BIN_SHIFT);
        unsigned slot = atomicAdd(&cur[b], 1u);
        unsigned long long pk = 0ull;   // neutral payload: adds 0.0 to node b*8192
        if (m0 < M_MAX && m1 < M_MAX) {
            unsigned fx0 = __float2uint_rn(m0 * FXS);
            unsigned fx1 = __float2uint_rn(m1 * FXS);
            pk = (unsigned long long)((unsigned)dst & (BIN_NODES - 1))
               | ((unsigned long long)fx0 << 13)
               | ((unsigned long long)fx1 << 38);
        } else {
            unsigned oi = atomicAdd(ovf_cnt, 1u);
            if (oi < OVF_CAP) ovf[oi] = make_float4(__int_as_float(dst), m0, m1, 0.f);
        }
        sorted[slot] = pk;
    }
    __syncthreads();

    // phase 4: coalesced flush — linear sweep, binary-search bin, dense store
    int ntot = (int)ntot_s;
    for (int p = t; p < ntot; p += P1_THREADS) {
        int lo = 0, hi = NB - 1;
        while (lo < hi) {                    // largest b with base[b] <= p
            int mid = (lo + hi + 1) >> 1;
            if ((int)base[mid] <= p) lo = mid; else hi = mid - 1;
        }
        unsigned gpos = gbase[lo] + (unsigned)(p - (int)base[lo]);
        unsigned long long v = sorted[p];
        if (gpos < BIN_CAP) {
            bins[(size_t)lo * BIN_CAP + gpos] = v;
        } else {                             // bin cap overflow: exact replay
            int local = (int)(v & (BIN_NODES - 1));
            float m0 = (float)((unsigned)((v >> 13) & 0x1FFFFFFu)) * FXI;
            float m1 = (float)((unsigned)((v >> 38) & 0x1FFFFFFu)) * FXI;
            int dst = (lo << BIN_SHIFT) + local;
            unsigned oi = atomicAdd(ovf_cnt, 1u);
            if (oi < OVF_CAP) ovf[oi] = make_float4(__int_as_float(dst), m0, m1, 0.f);
        }
    }
}

// ===========================================================================
// Pass 2: one block per bin; 64 KB LDS f32 slice, LDS atomics, coalesced
// slice store to aggf.
// ===========================================================================
__global__ __launch_bounds__(512) void p2_kernel(
    const unsigned long long* __restrict__ bins,
    const unsigned int* __restrict__ cursors,
    float* __restrict__ aggf)
{
    __shared__ float acc[BIN_NODES * 2];
    int b = blockIdx.x, t = threadIdx.x;
    for (int i = t; i < BIN_NODES * 2; i += 512) acc[i] = 0.f;
    __syncthreads();

    int n = (int)min(cursors[b], (unsigned)BIN_CAP);
    const unsigned long long* bp = bins + (size_t)b * BIN_CAP;
    for (int i = t; i < n; i += 512) {
        unsigned long long v = bp[i];
        int local = (int)(v & (BIN_NODES - 1));
        float m0 = (float)((unsigned)((v >> 13) & 0x1FFFFFFu)) * FXI;
        float m1 = (float)((unsigned)((v >> 38) & 0x1FFFFFFu)) * FXI;
        atomicAdd(&acc[2 * local],     m0);
        atomicAdd(&acc[2 * local + 1], m1);
    }
    __syncthreads();

    int node0 = b << BIN_SHIFT;
    for (int i = t; i < BIN_NODES; i += 512) {
        int node = node0 + i;
        if (node < N_NODES)
            ((float2*)aggf)[node] = make_float2(acc[2 * i], acc[2 * i + 1]);
    }
}

// Replay overflow edges (statistically never occurs; correctness guard).
__global__ __launch_bounds__(256) void ovf_kernel(
    const float4* __restrict__ ovf, const unsigned int* __restrict__ ovf_cnt,
    float* __restrict__ aggf)
{
    int n = (int)min(*ovf_cnt, (unsigned)OVF_CAP);
    for (int i = threadIdx.x; i < n; i += 256) {
        float4 r = ovf[i];
        int dst = __float_as_int(r.x);
        unsafeAtomicAdd(&aggf[2 * dst],     r.y);
        unsafeAtomicAdd(&aggf[2 * dst + 1], r.z);
    }
}

// Segment boundaries of sorted batch -> starts[0..N_GRAPHS].
__global__ __launch_bounds__(256) void starts_kernel(
    const int* __restrict__ batch, unsigned int* __restrict__ starts)
{
    int i = blockIdx.x * 256 + threadIdx.x;
    if (i >= N_NODES) return;
    int b1 = batch[i];
    if (i == 0) {
        for (int g = 0; g <= b1; ++g) starts[g] = 0;
    } else {
        int b0 = batch[i - 1];
        for (int g = b0 + 1; g <= b1; ++g) starts[g] = i;
    }
    if (i == N_NODES - 1) {
        for (int g = b1 + 1; g <= N_GRAPHS; ++g) starts[g] = N_NODES;
    }
}

// Pool: 4 graphs per 256-thread block (one wave each).
__global__ __launch_bounds__(256) void pool2_kernel(
    const float* __restrict__ x, const float* __restrict__ aggf,
    const unsigned int* __restrict__ starts,
    const float* __restrict__ W1, const float* __restrict__ b1,
    float* __restrict__ mean_out)
{
    int wave = threadIdx.x >> 6, lane = threadIdx.x & 63;
    int g = blockIdx.x * 4 + wave;

    float w00 = W1[0], w01 = W1[1], w02 = W1[2];
    float w10 = W1[3], w11 = W1[4], w12 = W1[5];
    float c0 = b1[0], c1 = b1[1], c2 = b1[2];

    int s = (int)starts[g], e = (int)starts[g + 1];
    float a0 = 0.f, a1 = 0.f, a2 = 0.f;
    for (int i = s + lane; i < e; i += 64) {
        float2 xv = ((const float2*)x)[i];
        float2 gv = ((const float2*)aggf)[i];
        float h0 = xv.x + gv.x;
        float h1 = xv.y + gv.y;
        a0 += fmaxf(h0*w00 + h1*w10 + c0, 0.f);
        a1 += fmaxf(h0*w01 + h1*w11 + c1, 0.f);
        a2 += fmaxf(h0*w02 + h1*w12 + c2, 0.f);
    }
#pragma unroll
    for (int off = 32; off; off >>= 1) {
        a0 += __shfl_down(a0, off);
        a1 += __shfl_down(a1, off);
        a2 += __shfl_down(a2, off);
    }
    if (lane == 0) {
        float inv = 1.0f / fmaxf((float)(e - s), 1.0f);
        mean_out[3*(size_t)g]     = a0 * inv;
        mean_out[3*(size_t)g + 1] = a1 * inv;
        mean_out[3*(size_t)g + 2] = a2 * inv;
    }
}

// Final MLP + MSE loss (single block).
__global__ __launch_bounds__(1024) void final_kernel(
    const float* __restrict__ ma, const float* __restrict__ mb,
    const float* __restrict__ W2, const float* __restrict__ b2,
    const float* __restrict__ targets,
    float* __restrict__ out)
{
    __shared__ float red[1024];
    float w0 = W2[0], w1 = W2[1], w2 = W2[2], w3 = W2[3], w4 = W2[4], w5 = W2[5];
    float bias = b2[0];

    float lsum = 0.f;
    for (int g = threadIdx.x; g < N_GRAPHS; g += 1024) {
        float v = bias
                + ma[3*(size_t)g]*w0 + ma[3*(size_t)g+1]*w1 + ma[3*(size_t)g+2]*w2
                + mb[3*(size_t)g]*w3 + mb[3*(size_t)g+1]*w4 + mb[3*(size_t)g+2]*w5;
        v = fmaxf(v, 0.f);
        out[g] = v;
        float d = v - targets[g];
        lsum += d * d;
    }
    red[threadIdx.x] = lsum;
    __syncthreads();
#pragma unroll
    for (int off = 512; off; off >>= 1) {
        if (threadIdx.x < (unsigned)off) red[threadIdx.x] += red[threadIdx.x + off];
        __syncthreads();
    }
    if (threadIdx.x == 0) out[N_GRAPHS] = red[0] * (1.0f / (float)N_GRAPHS);
}

// ===========================================================================
// Fallback path (ws too small): R2's u64-packed global-atomic kernel.
// ===========================================================================
#define FB_SCALE 4194304.0f
#define FB_INV   2.384185791015625e-07f

__global__ __launch_bounds__(256) void fb_edge_kernel(
    const float* __restrict__ x, const int* __restrict__ ei,
    const float* __restrict__ ea,
    const float* __restrict__ Wf, const float* __restrict__ bfv,
    const float* __restrict__ Ws, const float* __restrict__ bsv,
    unsigned long long* __restrict__ agg)
{
    float wf[12], ws[12];
#pragma unroll
    for (int i = 0; i < 12; ++i) { wf[i] = Wf[i]; ws[i] = Ws[i]; }
    float bf0 = bfv[0], bf1 = bfv[1], bs0 = bsv[0], bs1 = bsv[1];

    int e = blockIdx.x * 256 + threadIdx.x;
    int src = ei[e];
    int dst = ei[N_EDGES + e];
    float2 xd = ((const float2*)x)[dst];
    float2 xs = ((const float2*)x)[src];
    float2 ev = ((const float2*)ea)[e];
    float z0 = xd.x, z1 = xd.y, z2 = xs.x, z3 = xs.y, z4 = ev.x, z5 = ev.y;

    float f0 = bf0 + z0*wf[0] + z1*wf[2] + z2*wf[4] + z3*wf[6] + z4*wf[8]  + z5*wf[10];
    float f1 = bf1 + z0*wf[1] + z1*wf[3] + z2*wf[5] + z3*wf[7] + z4*wf[9]  + z5*wf[11];
    float s0 = bs0 + z0*ws[0] + z1*ws[2] + z2*ws[4] + z3*ws[6] + z4*ws[8]  + z5*ws[10];
    float s1 = bs1 + z0*ws[1] + z1*ws[3] + z2*ws[5] + z3*ws[7] + z4*ws[9]  + z5*ws[11];

    float m0 = (1.f/(1.f+__expf(-f0))) * (fmaxf(s0,0.f) + __logf(1.f+__expf(-fabsf(s0))));
    float m1 = (1.f/(1.f+__expf(-f1))) * (fmaxf(s1,0.f) + __logf(1.f+__expf(-fabsf(s1))));

    unsigned int fx0 = __float2uint_rn(m0 * FB_SCALE);
    unsigned int fx1 = __float2uint_rn(m1 * FB_SCALE);
    atomicAdd(&agg[dst], (unsigned long long)fx0 | ((unsigned long long)fx1 << 32));
}

__global__ __launch_bounds__(64) void fb_pool_kernel(
    const float* __restrict__ x, const unsigned long long* __restrict__ agg,
    const int* __restrict__ batch,
    const float* __restrict__ W1, const float* __restrict__ b1,
    float* __restrict__ mean_out)
{
    int b = blockIdx.x;
    float w00 = W1[0], w01 = W1[1], w02 = W1[2];
    float w10 = W1[3], w11 = W1[4], w12 = W1[5];
    float c0 = b1[0], c1 = b1[1], c2 = b1[2];

    int lo = 0, hi = N_NODES;
    while (lo < hi) { int mid = (lo + hi) >> 1; if (batch[mid] < b) lo = mid + 1; else hi = mid; }
    int seg_s = lo;
    hi = N_NODES;
    while (lo < hi) { int mid = (lo + hi) >> 1; if (batch[mid] < b + 1) lo = mid + 1; else hi = mid; }
    int seg_e = lo;

    float a0 = 0.f, a1 = 0.f, a2 = 0.f;
    for (int i = seg_s + (int)threadIdx.x; i < seg_e; i += 64) {
        unsigned long long v = agg[i];
        float g0 = (float)(unsigned int)(v & 0xffffffffull) * FB_INV;
        float g1 = (float)(unsigned int)(v >> 32) * FB_INV;
        float2 xv = ((const float2*)x)[i];
        float h0 = xv.x + g0, h1 = xv.y + g1;
        a0 += fmaxf(h0*w00 + h1*w10 + c0, 0.f);
        a1 += fmaxf(h0*w01 + h1*w11 + c1, 0.f);
        a2 += fmaxf(h0*w02 + h1*w12 + c2, 0.f);
    }
#pragma unroll
    for (int off = 32; off; off >>= 1) {
        a0 += __shfl_down(a0, off);
        a1 += __shfl_down(a1, off);
        a2 += __shfl_down(a2, off);
    }
    if (threadIdx.x == 0) {
        float inv = 1.0f / fmaxf((float)(seg_e - seg_s), 1.0f);
        mean_out[3*(size_t)b]     = a0 * inv;
        mean_out[3*(size_t)b + 1] = a1 * inv;
        mean_out[3*(size_t)b + 2] = a2 * inv;
    }
}

extern "C" void kernel_launch(void* const* d_in, const int* in_sizes, int n_in,
                              void* d_out, int out_size, void* d_ws, size_t ws_size,
                              hipStream_t stream) {
    const float* x_a     = (const float*)d_in[0];
    const int*   ei_a    = (const int*)  d_in[1];
    const float* ea_a    = (const float*)d_in[2];
    const int*   batch_a = (const int*)  d_in[3];
    const float* x_b     = (const float*)d_in[4];
    const int*   ei_b    = (const int*)  d_in[5];
    const float* ea_b    = (const float*)d_in[6];
    const int*   batch_b = (const int*)  d_in[7];
    const float* targets = (const float*)d_in[8];
    const float* Wf = (const float*)d_in[10];
    const float* bf = (const float*)d_in[11];
    const float* Ws = (const float*)d_in[12];
    const float* bs = (const float*)d_in[13];
    const float* W1 = (const float*)d_in[14];
    const float* b1 = (const float*)d_in[15];
    const float* W2 = (const float*)d_in[16];
    const float* b2 = (const float*)d_in[17];
    float* out = (float*)d_out;
    char* ws = (char*)d_ws;

    if (ws_size >= WS_NEED) {
        unsigned int* curs_a   = (unsigned int*)(ws + OFF_CURS_A);
        unsigned int* curs_b   = (unsigned int*)(ws + OFF_CURS_B);
        unsigned int* ovfc_a   = (unsigned int*)(ws + OFF_OVFC_A);
        unsigned int* ovfc_b   = (unsigned int*)(ws + OFF_OVFC_B);
        unsigned int* starts_a = (unsigned int*)(ws + OFF_STARTS_A);
        unsigned int* starts_b = (unsigned int*)(ws + OFF_STARTS_B);
        float* mean_a = (float*)(ws + OFF_MEAN_A);
        float* mean_b = (float*)(ws + OFF_MEAN_B);
        float4* ovf_a = (float4*)(ws + OFF_OVF_A);
        float4* ovf_b = (float4*)(ws + OFF_OVF_B);
        float* aggf_a = (float*)(ws + OFF_AGGF_A);
        float* aggf_b = (float*)(ws + OFF_AGGF_B);
        unsigned long long* bins = (unsigned long long*)(ws + OFF_BINS);

        hipMemsetAsync(ws, 0, ZERO_SMALL, stream);

        int sgrid = (N_NODES + 255) / 256;
        starts_kernel<<<sgrid, 256, 0, stream>>>(batch_a, starts_a);
        starts_kernel<<<sgrid, 256, 0, stream>>>(batch_b, starts_b);

        p1_kernel<<<P1_GRID, P1_THREADS, 0, stream>>>(x_a, ei_a, ea_a, Wf, bf, Ws, bs,
                                                      bins, curs_a, ovfc_a, ovf_a);
        p2_kernel<<<NBINS, 512, 0, stream>>>(bins, curs_a, aggf_a);
        ovf_kernel<<<1, 256, 0, stream>>>(ovf_a, ovfc_a, aggf_a);

        p1_kernel<<<P1_GRID, P1_THREADS, 0, stream>>>(x_b, ei_b, ea_b, Wf, bf, Ws, bs,
                                                      bins, curs_b, ovfc_b, ovf_b);
        p2_kernel<<<NBINS, 512, 0, stream>>>(bins, curs_b, aggf_b);
        ovf_kernel<<<1, 256, 0, stream>>>(ovf_b, ovfc_b, aggf_b);

        pool2_kernel<<<N_GRAPHS / 4, 256, 0, stream>>>(x_a, aggf_a, starts_a, W1, b1, mean_a);
        pool2_kernel<<<N_GRAPHS / 4, 256, 0, stream>>>(x_b, aggf_b, starts_b, W1, b1, mean_b);

        final_kernel<<<1, 1024, 0, stream>>>(mean_a, mean_b, W2, b2, targets, out);
    } else {
        // Fallback: R2 path (u64 packed global atomics), needs ~8.1 MB ws.
        unsigned long long* aggu_a = (unsigned long long*)ws;
        unsigned long long* aggu_b = aggu_a + (size_t)N_NODES;
        float* mean_a = (float*)(aggu_b + (size_t)N_NODES);
        float* mean_b = mean_a + 3 * (size_t)N_GRAPHS;

        hipMemsetAsync(ws, 0, 2 * (size_t)N_NODES * sizeof(unsigned long long), stream);
        fb_edge_kernel<<<N_EDGES / 256, 256, 0, stream>>>(x_a, ei_a, ea_a, Wf, bf, Ws, bs, aggu_a);
        fb_edge_kernel<<<N_EDGES / 256, 256, 0, stream>>>(x_b, ei_b, ea_b, Wf, bf, Ws, bs, aggu_b);
        fb_pool_kernel<<<N_GRAPHS, 64, 0, stream>>>(x_a, aggu_a, batch_a, W1, b1, mean_a);
        fb_pool_kernel<<<N_GRAPHS, 64, 0, stream>>>(x_b, aggu_b, batch_b, W1, b1, mean_b);
        final_kernel<<<1, 1024, 0, stream>>>(mean_a, mean_b, W2, b2, targets, out);
    }
}

// Round 5
// 740.531 us; speedup vs baseline: 1.6454x; 1.6454x over previous
//
#include <hip/hip_runtime.h>

#define N_NODES 500000
#define N_EDGES 8000000
#define N_GRAPHS 4096

// ---------------- binned-aggregation v3 ----------------
// NB=128 bins of 4096 nodes; p1 block-sorts 8192 edges by bin and flushes
// coalesced runs (~64 edges = 512B) into exact per-bin regions reserved by
// one returning atomic per (block,bin). p2 splits each bin across K=4
// sub-blocks, each accumulating a private 32KB LDS slice -> plain stores to
// scratch. Pool sums the K slices directly (no combine, no aggf).
#define NB 128
#define BIN_SHIFT 12
#define BIN_NODES 4096
#define NBINS 123                   // ceil(500000/4096)
#define BIN_CAP 66560               // mean 65041, sigma ~254 -> +6sigma; ovf-safe
#define T_EDGES 8192
#define P1_THREADS 512
#define EPT (T_EDGES / P1_THREADS)  // 16
#define P1_GRID ((N_EDGES + T_EDGES - 1) / T_EDGES)   // 977
#define K 4                         // sub-blocks per bin in p2
#define P2_GRID (NBINS * K)         // 492
#define SLICE_F (BIN_NODES * 2)     // 8192 floats = 32KB per slice
#define FXS 131072.0f               // 2^17; fields 25b, m < 250
#define FXI (1.0f / 131072.0f)
#define M_MAX 250.0f
#define OVF_CAP 8192

// ---------------- ws layout (byte offsets) ----------------
#define OFF_CURS_A   0          // 128 u32
#define OFF_CURS_B   512
#define OFF_OVFC_A   1024
#define OFF_OVFC_B   1280
#define ZERO_SMALL   1536       // memset range per call
#define OFF_STARTS_A 4096       // 4097 u32, padded
#define OFF_STARTS_B 20736
#define OFF_MEAN_A   37376      // 4096*3 f32
#define OFF_MEAN_B   86528
#define OFF_OVF_A    135680     // 8192 float4
#define OFF_OVF_B    266752
#define OFF_SCRATCH  397824     // NBINS*K*SLICE_F f32 = 16,121,856 B (shared A/B)
#define OFF_BINS     16519680   // NBINS*BIN_CAP u64 = 65,495,040 B (shared A/B)
#define WS_NEED      82014720ull

// ===========================================================================
// Pass 1: LDS counting sort by dst bin, coalesced flush to reserved ranges.
// dst kept in VGPRs between histogram and compute phases (ei read once).
// ===========================================================================
__global__ __launch_bounds__(512, 4) void p1_kernel(
    const float* __restrict__ x, const int* __restrict__ ei,
    const float* __restrict__ ea,
    const float* __restrict__ Wf, const float* __restrict__ bfv,
    const float* __restrict__ Ws, const float* __restrict__ bsv,
    unsigned long long* __restrict__ bins, unsigned int* __restrict__ cursors,
    unsigned int* __restrict__ ovf_cnt, float4* __restrict__ ovf)
{
    __shared__ unsigned long long sorted[T_EDGES];   // 64 KB
    __shared__ unsigned int whist[8][NB];            // 4 KB
    __shared__ unsigned int base[NB];
    __shared__ unsigned int cur[NB];
    __shared__ unsigned int gbase[NB];
    __shared__ unsigned int ntot_s;

    int t = threadIdx.x;
    int wave = t >> 6;
    int ebase = blockIdx.x * T_EDGES;

    for (int i = t; i < 8 * NB; i += P1_THREADS) ((unsigned int*)whist)[i] = 0;
    __syncthreads();

    // phase 1: histogram; keep dst in registers for phase 3
    int d[EPT];
#pragma unroll
    for (int i = 0; i < EPT; ++i) {
        int e = ebase + i * P1_THREADS + t;
        d[i] = (e < N_EDGES) ? ei[N_EDGES + e] : -1;
        if (d[i] >= 0)
            atomicAdd(&whist[wave][((unsigned)d[i]) >> BIN_SHIFT], 1u);
    }
    __syncthreads();

    // phase 2: per-bin totals, exclusive scan (wave 0, 2 bins/lane), reserve
    if (t < 64) {
        unsigned tot0 = 0, tot1 = 0;
#pragma unroll
        for (int w = 0; w < 8; ++w) { tot0 += whist[w][2*t]; tot1 += whist[w][2*t+1]; }
        unsigned pair = tot0 + tot1;
        unsigned v = pair;
#pragma unroll
        for (int off = 1; off < 64; off <<= 1) {
            unsigned u = __shfl_up(v, off);
            if (t >= off) v += u;
        }
        unsigned excl = v - pair;
        base[2*t]   = excl;        cur[2*t]   = excl;
        base[2*t+1] = excl + tot0; cur[2*t+1] = excl + tot0;
        if (t == 63) ntot_s = v;
        gbase[2*t]   = tot0 ? atomicAdd(&cursors[2*t],   tot0) : 0u;
        gbase[2*t+1] = tot1 ? atomicAdd(&cursors[2*t+1], tot1) : 0u;
    }
    __syncthreads();

    // phase 3: compute m, place into sorted LDS slots
    float wf[12], wsv[12];
#pragma unroll
    for (int i = 0; i < 12; ++i) { wf[i] = Wf[i]; wsv[i] = Ws[i]; }
    float bf0 = bfv[0], bf1 = bfv[1], bs0 = bsv[0], bs1 = bsv[1];

#pragma unroll
    for (int i = 0; i < EPT; ++i) {
        int e = ebase + i * P1_THREADS + t;
        if (e >= N_EDGES) continue;
        int dst = d[i];
        int src = ei[e];
        float2 xd = ((const float2*)x)[dst];
        float2 xs = ((const float2*)x)[src];
        float2 ev = ((const float2*)ea)[e];
        float z0 = xd.x, z1 = xd.y, z2 = xs.x, z3 = xs.y, z4 = ev.x, z5 = ev.y;

        float f0 = bf0 + z0*wf[0] + z1*wf[2] + z2*wf[4] + z3*wf[6] + z4*wf[8]  + z5*wf[10];
        float f1 = bf1 + z0*wf[1] + z1*wf[3] + z2*wf[5] + z3*wf[7] + z4*wf[9]  + z5*wf[11];
        float s0 = bs0 + z0*wsv[0] + z1*wsv[2] + z2*wsv[4] + z3*wsv[6] + z4*wsv[8]  + z5*wsv[10];
        float s1 = bs1 + z0*wsv[1] + z1*wsv[3] + z2*wsv[5] + z3*wsv[7] + z4*wsv[9]  + z5*wsv[11];

        float m0 = (1.f/(1.f+__expf(-f0))) * (fmaxf(s0,0.f) + __logf(1.f+__expf(-fabsf(s0))));
        float m1 = (1.f/(1.f+__expf(-f1))) * (fmaxf(s1,0.f) + __logf(1.f+__expf(-fabsf(s1))));

        int b = (int)((unsigned)dst >> BIN_SHIFT);
        unsigned slot = atomicAdd(&cur[b], 1u);
        unsigned long long pk = 0ull;     // neutral: adds 0.0 to node b<<12
        if (m0 < M_MAX && m1 < M_MAX) {
            unsigned fx0 = __float2uint_rn(m0 * FXS);
            unsigned fx1 = __float2uint_rn(m1 * FXS);
            pk = (unsigned long long)((unsigned)dst & (BIN_NODES - 1))
               | ((unsigned long long)fx0 << 12)
               | ((unsigned long long)fx1 << 37);
        } else {
            unsigned oi = atomicAdd(ovf_cnt, 1u);
            if (oi < OVF_CAP) ovf[oi] = make_float4(__int_as_float(dst), m0, m1, 0.f);
        }
        sorted[slot] = pk;
    }
    __syncthreads();

    // phase 4: coalesced flush (runs of ~64 edges = 512B contiguous)
    int ntot = (int)ntot_s;
    for (int p = t; p < ntot; p += P1_THREADS) {
        int lo = 0, hi = NB - 1;
        while (lo < hi) {                 // largest b with base[b] <= p
            int mid = (lo + hi + 1) >> 1;
            if ((int)base[mid] <= p) lo = mid; else hi = mid - 1;
        }
        unsigned gpos = gbase[lo] + (unsigned)(p - (int)base[lo]);
        unsigned long long v = sorted[p];
        if (gpos < BIN_CAP) {
            bins[(size_t)lo * BIN_CAP + gpos] = v;
        } else {                          // cap overflow (p~1e-9): exact replay
            int local = (int)(v & (BIN_NODES - 1));
            float m0 = (float)((unsigned)((v >> 12) & 0x1FFFFFFu)) * FXI;
            float m1 = (float)((unsigned)((v >> 37) & 0x1FFFFFFu)) * FXI;
            int dst = (lo << BIN_SHIFT) + local;
            unsigned oi = atomicAdd(ovf_cnt, 1u);
            if (oi < OVF_CAP) ovf[oi] = make_float4(__int_as_float(dst), m0, m1, 0.f);
        }
    }
}

// ===========================================================================
// Pass 2: K=4 sub-blocks per bin; 32KB private LDS slice + LDS atomics;
// plain coalesced float4 stores of the slice to scratch.
// ===========================================================================
__global__ __launch_bounds__(512, 8) void p2_kernel(
    const unsigned long long* __restrict__ bins,
    const unsigned int* __restrict__ cursors,
    float* __restrict__ scratch)
{
    __shared__ float acc[SLICE_F];        // 32 KB
    int b = blockIdx.x >> 2;
    int k = blockIdx.x & 3;
    int t = threadIdx.x;
#pragma unroll
    for (int i = t; i < SLICE_F; i += 512) acc[i] = 0.f;
    __syncthreads();

    int n = (int)min(cursors[b], (unsigned)BIN_CAP);
    int s = (n * k) / K, e = (n * (k + 1)) / K;
    const unsigned long long* bp = bins + (size_t)b * BIN_CAP;
    for (int i = s + t; i < e; i += 512) {
        unsigned long long v = bp[i];
        int local = (int)(v & (BIN_NODES - 1));
        float m0 = (float)((unsigned)((v >> 12) & 0x1FFFFFFu)) * FXI;
        float m1 = (float)((unsigned)((v >> 37) & 0x1FFFFFFu)) * FXI;
        atomicAdd(&acc[2 * local],     m0);
        atomicAdd(&acc[2 * local + 1], m1);
    }
    __syncthreads();

    float4* dst = (float4*)(scratch + (size_t)(b * K + k) * SLICE_F);
    const float4* src = (const float4*)acc;
#pragma unroll
    for (int i = t; i < SLICE_F / 4; i += 512) dst[i] = src[i];
}

// Replay overflow edges into slice k=0 (statistically never taken).
__global__ __launch_bounds__(256) void ovf_kernel(
    const float4* __restrict__ ovf, const unsigned int* __restrict__ ovf_cnt,
    float* __restrict__ scratch)
{
    int n = (int)min(*ovf_cnt, (unsigned)OVF_CAP);
    for (int i = threadIdx.x; i < n; i += 256) {
        float4 r = ovf[i];
        int dst = __float_as_int(r.x);
        int b = dst >> BIN_SHIFT, local = dst & (BIN_NODES - 1);
        float* p = scratch + (size_t)(b * K) * SLICE_F + 2 * local;
        unsafeAtomicAdd(p,     r.y);
        unsafeAtomicAdd(p + 1, r.z);
    }
}

// Segment boundaries of sorted batch -> starts[0..N_GRAPHS].
__global__ __launch_bounds__(256) void starts_kernel(
    const int* __restrict__ batch, unsigned int* __restrict__ starts)
{
    int i = blockIdx.x * 256 + threadIdx.x;
    if (i >= N_NODES) return;
    int b1 = batch[i];
    if (i == 0) {
        for (int g = 0; g <= b1; ++g) starts[g] = 0;
    } else {
        int b0 = batch[i - 1];
        for (int g = b0 + 1; g <= b1; ++g) starts[g] = i;
    }
    if (i == N_NODES - 1) {
        for (int g = b1 + 1; g <= N_GRAPHS; ++g) starts[g] = N_NODES;
    }
}

// Pool: 4 graphs per block (one wave each); agg = sum of K slices, read
// directly from scratch (consecutive nodes -> coalesced in each slice).
__global__ __launch_bounds__(256) void pool2_kernel(
    const float* __restrict__ x, const float* __restrict__ scratch,
    const unsigned int* __restrict__ starts,
    const float* __restrict__ W1, const float* __restrict__ b1,
    float* __restrict__ mean_out)
{
    int wave = threadIdx.x >> 6, lane = threadIdx.x & 63;
    int g = blockIdx.x * 4 + wave;

    float w00 = W1[0], w01 = W1[1], w02 = W1[2];
    float w10 = W1[3], w11 = W1[4], w12 = W1[5];
    float c0 = b1[0], c1 = b1[1], c2 = b1[2];

    const float2* sc2 = (const float2*)scratch;
    int s = (int)starts[g], e = (int)starts[g + 1];
    float a0 = 0.f, a1 = 0.f, a2 = 0.f;
    for (int i = s + lane; i < e; i += 64) {
        int b = i >> BIN_SHIFT, local = i & (BIN_NODES - 1);
        size_t f2base = (size_t)b * (K * BIN_NODES) + local;   // slice stride 4096 f2
        float2 g0 = sc2[f2base];
        float2 g1 = sc2[f2base + BIN_NODES];
        float2 g2 = sc2[f2base + 2 * BIN_NODES];
        float2 g3 = sc2[f2base + 3 * BIN_NODES];
        float2 xv = ((const float2*)x)[i];
        float h0 = xv.x + g0.x + g1.x + g2.x + g3.x;
        float h1 = xv.y + g0.y + g1.y + g2.y + g3.y;
        a0 += fmaxf(h0*w00 + h1*w10 + c0, 0.f);
        a1 += fmaxf(h0*w01 + h1*w11 + c1, 0.f);
        a2 += fmaxf(h0*w02 + h1*w12 + c2, 0.f);
    }
#pragma unroll
    for (int off = 32; off; off >>= 1) {
        a0 += __shfl_down(a0, off);
        a1 += __shfl_down(a1, off);
        a2 += __shfl_down(a2, off);
    }
    if (lane == 0) {
        float inv = 1.0f / fmaxf((float)(e - s), 1.0f);
        mean_out[3*(size_t)g]     = a0 * inv;
        mean_out[3*(size_t)g + 1] = a1 * inv;
        mean_out[3*(size_t)g + 2] = a2 * inv;
    }
}

// Final MLP + MSE loss (single block).
__global__ __launch_bounds__(1024) void final_kernel(
    const float* __restrict__ ma, const float* __restrict__ mb,
    const float* __restrict__ W2, const float* __restrict__ b2,
    const float* __restrict__ targets,
    float* __restrict__ out)
{
    __shared__ float red[1024];
    float w0 = W2[0], w1 = W2[1], w2 = W2[2], w3 = W2[3], w4 = W2[4], w5 = W2[5];
    float bias = b2[0];

    float lsum = 0.f;
    for (int g = threadIdx.x; g < N_GRAPHS; g += 1024) {
        float v = bias
                + ma[3*(size_t)g]*w0 + ma[3*(size_t)g+1]*w1 + ma[3*(size_t)g+2]*w2
                + mb[3*(size_t)g]*w3 + mb[3*(size_t)g+1]*w4 + mb[3*(size_t)g+2]*w5;
        v = fmaxf(v, 0.f);
        out[g] = v;
        float d = v - targets[g];
        lsum += d * d;
    }
    red[threadIdx.x] = lsum;
    __syncthreads();
#pragma unroll
    for (int off = 512; off; off >>= 1) {
        if (threadIdx.x < (unsigned)off) red[threadIdx.x] += red[threadIdx.x + off];
        __syncthreads();
    }
    if (threadIdx.x == 0) out[N_GRAPHS] = red[0] * (1.0f / (float)N_GRAPHS);
}

// ===========================================================================
// Fallback path (ws too small): R2's u64-packed global-atomic kernel.
// ===========================================================================
#define FB_SCALE 4194304.0f
#define FB_INV   2.384185791015625e-07f

__global__ __launch_bounds__(256) void fb_edge_kernel(
    const float* __restrict__ x, const int* __restrict__ ei,
    const float* __restrict__ ea,
    const float* __restrict__ Wf, const float* __restrict__ bfv,
    const float* __restrict__ Ws, const float* __restrict__ bsv,
    unsigned long long* __restrict__ agg)
{
    float wf[12], ws[12];
#pragma unroll
    for (int i = 0; i < 12; ++i) { wf[i] = Wf[i]; ws[i] = Ws[i]; }
    float bf0 = bfv[0], bf1 = bfv[1], bs0 = bsv[0], bs1 = bsv[1];

    int e = blockIdx.x * 256 + threadIdx.x;
    int src = ei[e];
    int dst = ei[N_EDGES + e];
    float2 xd = ((const float2*)x)[dst];
    float2 xs = ((const float2*)x)[src];
    float2 ev = ((const float2*)ea)[e];
    float z0 = xd.x, z1 = xd.y, z2 = xs.x, z3 = xs.y, z4 = ev.x, z5 = ev.y;

    float f0 = bf0 + z0*wf[0] + z1*wf[2] + z2*wf[4] + z3*wf[6] + z4*wf[8]  + z5*wf[10];
    float f1 = bf1 + z0*wf[1] + z1*wf[3] + z2*wf[5] + z3*wf[7] + z4*wf[9]  + z5*wf[11];
    float s0 = bs0 + z0*ws[0] + z1*ws[2] + z2*ws[4] + z3*ws[6] + z4*ws[8]  + z5*ws[10];
    float s1 = bs1 + z0*ws[1] + z1*ws[3] + z2*ws[5] + z3*ws[7] + z4*ws[9]  + z5*ws[11];

    float m0 = (1.f/(1.f+__expf(-f0))) * (fmaxf(s0,0.f) + __logf(1.f+__expf(-fabsf(s0))));
    float m1 = (1.f/(1.f+__expf(-f1))) * (fmaxf(s1,0.f) + __logf(1.f+__expf(-fabsf(s1))));

    unsigned int fx0 = __float2uint_rn(m0 * FB_SCALE);
    unsigned int fx1 = __float2uint_rn(m1 * FB_SCALE);
    atomicAdd(&agg[dst], (unsigned long long)fx0 | ((unsigned long long)fx1 << 32));
}

__global__ __launch_bounds__(64) void fb_pool_kernel(
    const float* __restrict__ x, const unsigned long long* __restrict__ agg,
    const int* __restrict__ batch,
    const float* __restrict__ W1, const float* __restrict__ b1,
    float* __restrict__ mean_out)
{
    int b = blockIdx.x;
    float w00 = W1[0], w01 = W1[1], w02 = W1[2];
    float w10 = W1[3], w11 = W1[4], w12 = W1[5];
    float c0 = b1[0], c1 = b1[1], c2 = b1[2];

    int lo = 0, hi = N_NODES;
    while (lo < hi) { int mid = (lo + hi) >> 1; if (batch[mid] < b) lo = mid + 1; else hi = mid; }
    int seg_s = lo;
    hi = N_NODES;
    while (lo < hi) { int mid = (lo + hi) >> 1; if (batch[mid] < b + 1) lo = mid + 1; else hi = mid; }
    int seg_e = lo;

    float a0 = 0.f, a1 = 0.f, a2 = 0.f;
    for (int i = seg_s + (int)threadIdx.x; i < seg_e; i += 64) {
        unsigned long long v = agg[i];
        float g0 = (float)(unsigned int)(v & 0xffffffffull) * FB_INV;
        float g1 = (float)(unsigned int)(v >> 32) * FB_INV;
        float2 xv = ((const float2*)x)[i];
        float h0 = xv.x + g0, h1 = xv.y + g1;
        a0 += fmaxf(h0*w00 + h1*w10 + c0, 0.f);
        a1 += fmaxf(h0*w01 + h1*w11 + c1, 0.f);
        a2 += fmaxf(h0*w02 + h1*w12 + c2, 0.f);
    }
#pragma unroll
    for (int off = 32; off; off >>= 1) {
        a0 += __shfl_down(a0, off);
        a1 += __shfl_down(a1, off);
        a2 += __shfl_down(a2, off);
    }
    if (threadIdx.x == 0) {
        float inv = 1.0f / fmaxf((float)(seg_e - seg_s), 1.0f);
        mean_out[3*(size_t)b]     = a0 * inv;
        mean_out[3*(size_t)b + 1] = a1 * inv;
        mean_out[3*(size_t)b + 2] = a2 * inv;
    }
}

extern "C" void kernel_launch(void* const* d_in, const int* in_sizes, int n_in,
                              void* d_out, int out_size, void* d_ws, size_t ws_size,
                              hipStream_t stream) {
    const float* x_a     = (const float*)d_in[0];
    const int*   ei_a    = (const int*)  d_in[1];
    const float* ea_a    = (const float*)d_in[2];
    const int*   batch_a = (const int*)  d_in[3];
    const float* x_b     = (const float*)d_in[4];
    const int*   ei_b    = (const int*)  d_in[5];
    const float* ea_b    = (const float*)d_in[6];
    const int*   batch_b = (const int*)  d_in[7];
    const float* targets = (const float*)d_in[8];
    const float* Wf = (const float*)d_in[10];
    const float* bf = (const float*)d_in[11];
    const float* Ws = (const float*)d_in[12];
    const float* bs = (const float*)d_in[13];
    const float* W1 = (const float*)d_in[14];
    const float* b1 = (const float*)d_in[15];
    const float* W2 = (const float*)d_in[16];
    const float* b2 = (const float*)d_in[17];
    float* out = (float*)d_out;
    char* ws = (char*)d_ws;

    if (ws_size >= WS_NEED) {
        unsigned int* curs_a   = (unsigned int*)(ws + OFF_CURS_A);
        unsigned int* curs_b   = (unsigned int*)(ws + OFF_CURS_B);
        unsigned int* ovfc_a   = (unsigned int*)(ws + OFF_OVFC_A);
        unsigned int* ovfc_b   = (unsigned int*)(ws + OFF_OVFC_B);
        unsigned int* starts_a = (unsigned int*)(ws + OFF_STARTS_A);
        unsigned int* starts_b = (unsigned int*)(ws + OFF_STARTS_B);
        float* mean_a = (float*)(ws + OFF_MEAN_A);
        float* mean_b = (float*)(ws + OFF_MEAN_B);
        float4* ovf_a = (float4*)(ws + OFF_OVF_A);
        float4* ovf_b = (float4*)(ws + OFF_OVF_B);
        float* scratch = (float*)(ws + OFF_SCRATCH);            // shared A/B
        unsigned long long* bins = (unsigned long long*)(ws + OFF_BINS);

        hipMemsetAsync(ws, 0, ZERO_SMALL, stream);

        int sgrid = (N_NODES + 255) / 256;
        starts_kernel<<<sgrid, 256, 0, stream>>>(batch_a, starts_a);
        starts_kernel<<<sgrid, 256, 0, stream>>>(batch_b, starts_b);

        // branch A (pool_a must precede p2_b: scratch is reused)
        p1_kernel<<<P1_GRID, P1_THREADS, 0, stream>>>(x_a, ei_a, ea_a, Wf, bf, Ws, bs,
                                                      bins, curs_a, ovfc_a, ovf_a);
        p2_kernel<<<P2_GRID, 512, 0, stream>>>(bins, curs_a, scratch);
        ovf_kernel<<<1, 256, 0, stream>>>(ovf_a, ovfc_a, scratch);
        pool2_kernel<<<N_GRAPHS / 4, 256, 0, stream>>>(x_a, scratch, starts_a, W1, b1, mean_a);

        // branch B
        p1_kernel<<<P1_GRID, P1_THREADS, 0, stream>>>(x_b, ei_b, ea_b, Wf, bf, Ws, bs,
                                                      bins, curs_b, ovfc_b, ovf_b);
        p2_kernel<<<P2_GRID, 512, 0, stream>>>(bins, curs_b, scratch);
        ovf_kernel<<<1, 256, 0, stream>>>(ovf_b, ovfc_b, scratch);
        pool2_kernel<<<N_GRAPHS / 4, 256, 0, stream>>>(x_b, scratch, starts_b, W1, b1, mean_b);

        final_kernel<<<1, 1024, 0, stream>>>(mean_a, mean_b, W2, b2, targets, out);
    } else {
        // Fallback: R2 path (u64 packed global atomics), needs ~8.1 MB ws.
        unsigned long long* aggu_a = (unsigned long long*)ws;
        unsigned long long* aggu_b = aggu_a + (size_t)N_NODES;
        float* mean_a = (float*)(aggu_b + (size_t)N_NODES);
        float* mean_b = mean_a + 3 * (size_t)N_GRAPHS;

        hipMemsetAsync(ws, 0, 2 * (size_t)N_NODES * sizeof(unsigned long long), stream);
        fb_edge_kernel<<<N_EDGES / 256, 256, 0, stream>>>(x_a, ei_a, ea_a, Wf, bf, Ws, bs, aggu_a);
        fb_edge_kernel<<<N_EDGES / 256, 256, 0, stream>>>(x_b, ei_b, ea_b, Wf, bf, Ws, bs, aggu_b);
        fb_pool_kernel<<<N_GRAPHS, 64, 0, stream>>>(x_a, aggu_a, batch_a, W1, b1, mean_a);
        fb_pool_kernel<<<N_GRAPHS, 64, 0, stream>>>(x_b, aggu_b, batch_b, W1, b1, mean_b);
        final_kernel<<<1, 1024, 0, stream>>>(mean_a, mean_b, W2, b2, targets, out);
    }
}